// Round 5
// baseline (1341.659 us; speedup 1.0000x reference)
//
#include <hip/hip_runtime.h>
#include <hip/hip_bf16.h>
#include <stdint.h>

#define B_ 32
#define T_ 2048
#define D_ 1024
#define N_ 1024
#define M_ (B_*T_)

// k2 geometry: 128x256 tile, BK=32, 8 waves (2Mx4N), wave tile 64x64
#define BM 128
#define BN 256
#define BK 32
#define NSTEP 128          // 4 nt-passes * 32 k-steps
// per-buffer: A bf16 8KB | Bh 16KB | Bl 16KB = 40KB; double buffer = 80KB -> 2 blocks/CU
#define BHOFF 8192
#define BLOFF 24576
#define BUFB  40960
#define SMEM_TOTAL (2 * BUFB)

typedef short bf16x8 __attribute__((ext_vector_type(8)));
typedef float f32x4 __attribute__((ext_vector_type(4)));

__device__ __forceinline__ unsigned short bf16_rn(float x) {
    unsigned u = __float_as_uint(x);
    u += 0x7FFFu + ((u >> 16) & 1u);
    return (unsigned short)(u >> 16);
}

__device__ __forceinline__ void gload_lds16(const void* g, void* l) {
    __builtin_amdgcn_global_load_lds(
        (__attribute__((address_space(1))) void*)(g),
        (__attribute__((address_space(3))) void*)(l), 16, 0, 0);
}

// K0: W2 [D][N] fp32 -> W2T hi/lo bf16 [N][D]
__global__ void k0_w2t(const float* __restrict__ W2,
                       unsigned short* __restrict__ Th,
                       unsigned short* __restrict__ Tl) {
    __shared__ float tile[32][33];
    int n0 = blockIdx.x * 32, d0 = blockIdx.y * 32;
    int tx = threadIdx.x & 31, ty = threadIdx.x >> 5; // 32 x 8
    #pragma unroll
    for (int i = 0; i < 4; i++) {
        int d = d0 + ty + i * 8;
        tile[ty + i * 8][tx] = W2[d * N_ + n0 + tx];
    }
    __syncthreads();
    #pragma unroll
    for (int i = 0; i < 4; i++) {
        int n = n0 + ty + i * 8;
        float v = tile[tx][ty + i * 8];
        unsigned short h = bf16_rn(v);
        float hf = __uint_as_float((unsigned)h << 16);
        unsigned short l = bf16_rn(v - hf);
        Th[n * D_ + d0 + tx] = h;
        Tl[n * D_ + d0 + tx] = l;
    }
}

// K1: q_proj[b][n] = query[b]@W1[:,n] + b1[n]   (fp32)
__global__ void k1_qproj(const float* __restrict__ query,
                         const float* __restrict__ W1,
                         const float* __restrict__ b1,
                         float* __restrict__ qp) {
    int b = blockIdx.x;
    int n = blockIdx.y * 256 + threadIdx.x;
    const float* q = query + b * D_;
    const float* w = W1 + n;
    float s = 0.f;
    #pragma unroll 8
    for (int d = 0; d < D_; d++) s += q[d] * w[d * N_];
    qp[b * N_ + n] = s + b1[n];
}

// B staging: [g 0..3][256 rows][8 bf16] per array; 2 gload_lds16 per thread.
__device__ __forceinline__ void stage_B(char* buf, int off, int u, int w, int lane,
                                        const unsigned short* __restrict__ W) {
    const int k0 = (u & 31) * BK;
    const int nt = u >> 5;
    #pragma unroll
    for (int i = 0; i < 2; i++) {
        int c = (w + i * 8) * 64 + lane;
        int g = c >> 8;
        int row = c & 255;
        const unsigned short* src = W + (size_t)(nt * BN + row) * D_ + k0 + g * 8;
        char* dst = buf + off + (w + i * 8) * 1024;
        gload_lds16(src, dst);
    }
}

__device__ __forceinline__ short bf16s(float f) {
    __hip_bfloat16 h = __float2bfloat16(f);   // RTN; compiler packs pairs
    return *reinterpret_cast<short*>(&h);
}
__device__ __forceinline__ bf16x8 cvt8(float4 x, float4 y) {
    bf16x8 r;
    r[0] = bf16s(x.x); r[1] = bf16s(x.y); r[2] = bf16s(x.z); r[3] = bf16s(x.w);
    r[4] = bf16s(y.x); r[5] = bf16s(y.y); r[6] = bf16s(y.z); r[7] = bf16s(y.w);
    return r;
}

#define MFMA2(a, bh, bl, A) do { \
    (A) = __builtin_amdgcn_mfma_f32_16x16x32_bf16((a), (bh), (A), 0, 0, 0); \
    (A) = __builtin_amdgcn_mfma_f32_16x16x32_bf16((a), (bl), (A), 0, 0, 0); \
} while (0)

// K2: fused score GEMM. A single bf16 (converted ONCE at staging, reg->LDS),
// B bf16 hi/lo via global_load_lds. One barrier per K-step, double-buffered,
// loads issued at step start (T14), 2 blocks/CU for cross-block overlap.
__global__ __launch_bounds__(512, 4) void k2_score(
    const float* __restrict__ values,
    const unsigned short* __restrict__ W2Th,
    const unsigned short* __restrict__ W2Tl,
    const float* __restrict__ qp,
    const float* __restrict__ b2,
    const float* __restrict__ V,
    const float* __restrict__ bV,
    float* __restrict__ score) {
    extern __shared__ char smem[];

    const int tid = threadIdx.x;
    const int lane = tid & 63;
    const int w = tid >> 6;       // 0..7
    const int wm = w >> 2;        // 0..1  (M waves)
    const int wn = w & 3;         // 0..3  (N waves)
    const int c16 = lane & 15;
    const int g = lane >> 4;      // 0..3 k-group
    const int m0 = blockIdx.x * BM;
    const int b = m0 >> 11;       // m0 / T_

    // A staging mapping: thread -> (row, ks); global 32B contiguous per thread,
    // LDS write at [ks][row ^ (ks<<2)] (XOR swizzle, both sides).
    const int row_a = tid >> 2;   // 0..127
    const int ks_a = tid & 3;     // 0..3

    f32x4 acc[4][4];
    #pragma unroll
    for (int mi = 0; mi < 4; mi++)
        #pragma unroll
        for (int ni = 0; ni < 4; ni++) {
            f32x4 z = {0.f, 0.f, 0.f, 0.f};
            acc[mi][ni] = z;
        }
    float rowpart[16];
    #pragma unroll
    for (int i = 0; i < 16; i++) rowpart[i] = 0.f;

    // prologue: stage step 0 into buf0
    {
        const float* asrc = values + (size_t)(m0 + row_a) * D_ + ks_a * 8;
        float4 v0 = *(const float4*)(asrc);
        float4 v1 = *(const float4*)(asrc + 4);
        stage_B(smem, BHOFF, 0, w, lane, W2Th);
        stage_B(smem, BLOFF, 0, w, lane, W2Tl);
        bf16x8 aw = cvt8(v0, v1);
        *(bf16x8*)(smem + ks_a * 2048 + ((row_a ^ (ks_a << 2)) * 16)) = aw;
    }
    __syncthreads();

    for (int s = 0; s < NSTEP; ++s) {
        char* buf  = smem + (s & 1) * BUFB;
        char* bufn = smem + ((s + 1) & 1) * BUFB;
        const bool st = (s + 1) < NSTEP;

        // issue next step's loads FIRST: A globals (reg), then B gload_lds.
        // (A issued first so its implicit vmcnt wait leaves B loads in flight)
        float4 av0, av1;
        if (st) {
            int kt1 = (s + 1) & 31;
            const float* asrc = values + (size_t)(m0 + row_a) * D_ + kt1 * BK + ks_a * 8;
            av0 = *(const float4*)(asrc);
            av1 = *(const float4*)(asrc + 4);
            stage_B(bufn, BHOFF, s + 1, w, lane, W2Th);
            stage_B(bufn, BLOFF, s + 1, w, lane, W2Tl);
        }

        // read B frags (current buffer)
        const char* bhP = buf + BHOFF + g * 4096 + (wn * 64 + c16) * 16;
        const char* blP = buf + BLOFF + g * 4096 + (wn * 64 + c16) * 16;
        bf16x8 bh[4], bl[4];
        #pragma unroll
        for (int ni = 0; ni < 4; ni++) {
            bh[ni] = *(const bf16x8*)(bhP + ni * 256);
            bl[ni] = *(const bf16x8*)(blP + ni * 256);
        }

        // stage A for next step (cvt once, single ds_write_b128)
        if (st) {
            bf16x8 aw = cvt8(av0, av1);
            *(bf16x8*)(bufn + ks_a * 2048 + ((row_a ^ (ks_a << 2)) * 16)) = aw;
        }

        // MFMA: per-mi A-frag read (keeps VGPR <= 128 for 2 blocks/CU)
        const char* aR = buf + g * 2048;
        __builtin_amdgcn_s_setprio(1);
        #pragma unroll
        for (int mi = 0; mi < 4; mi++) {
            int r = wm * 64 + mi * 16 + c16;
            bf16x8 af = *(const bf16x8*)(aR + ((r ^ (g << 2)) * 16));
            #pragma unroll
            for (int ni = 0; ni < 4; ni++)
                MFMA2(af, bh[ni], bl[ni], acc[mi][ni]);
        }
        __builtin_amdgcn_s_setprio(0);

        // nt-pass epilogue: fold acc into rowpart via tanh
        if ((s & 31) == 31) {
            int nt = s >> 5;
            #pragma unroll
            for (int ni = 0; ni < 4; ni++) {
                int n = nt * BN + wn * 64 + ni * 16 + c16;
                float qv = qp[b * N_ + n] + b2[n];
                float Vv = V[n];
                #pragma unroll
                for (int mi = 0; mi < 4; mi++)
                    #pragma unroll
                    for (int r = 0; r < 4; r++)
                        rowpart[mi * 4 + r] += tanhf(acc[mi][ni][r] + qv) * Vv;
            }
            #pragma unroll
            for (int mi = 0; mi < 4; mi++)
                #pragma unroll
                for (int ni = 0; ni < 4; ni++) {
                    f32x4 z = {0.f, 0.f, 0.f, 0.f};
                    acc[mi][ni] = z;
                }
        }

        __syncthreads();  // drains vmcnt (gload_lds) + lgkm (ds_write); buffers flip
    }

    // final reduction: 16 n-lanes, then across the 4 wn waves via LDS
    #pragma unroll
    for (int i = 0; i < 16; i++) {
        float v = rowpart[i];
        v += __shfl_xor(v, 1);
        v += __shfl_xor(v, 2);
        v += __shfl_xor(v, 4);
        v += __shfl_xor(v, 8);
        rowpart[i] = v;
    }
    float* red = (float*)smem;  // aliases staging buffers (loop done)
    if (c16 == 0) {
        #pragma unroll
        for (int mi = 0; mi < 4; mi++)
            #pragma unroll
            for (int r = 0; r < 4; r++)
                red[wn * BM + wm * 64 + mi * 16 + g * 4 + r] = rowpart[mi * 4 + r];
    }
    __syncthreads();
    if (tid < BM) {
        score[m0 + tid] = red[tid] + red[BM + tid] + red[2 * BM + tid] + red[3 * BM + tid] + bV[0];
    }
}

// K3: softmax over T per batch, in place
__global__ void k3_softmax(float* __restrict__ sw) {
    int b = blockIdx.x;
    float* row = sw + b * T_;
    int tid = threadIdx.x;
    float v[8];
    float lmax = -1e30f;
    #pragma unroll
    for (int i = 0; i < 8; i++) {
        v[i] = row[tid + i * 256];
        lmax = fmaxf(lmax, v[i]);
    }
    #pragma unroll
    for (int d = 1; d < 64; d <<= 1) lmax = fmaxf(lmax, __shfl_xor(lmax, d));
    __shared__ float sm[4], ss[4];
    if ((tid & 63) == 0) sm[tid >> 6] = lmax;
    __syncthreads();
    lmax = fmaxf(fmaxf(sm[0], sm[1]), fmaxf(sm[2], sm[3]));
    float lsum = 0.f;
    #pragma unroll
    for (int i = 0; i < 8; i++) {
        v[i] = expf(v[i] - lmax);
        lsum += v[i];
    }
    #pragma unroll
    for (int d = 1; d < 64; d <<= 1) lsum += __shfl_xor(lsum, d);
    if ((tid & 63) == 0) ss[tid >> 6] = lsum;
    __syncthreads();
    lsum = ss[0] + ss[1] + ss[2] + ss[3];
    float inv = 1.f / lsum;
    #pragma unroll
    for (int i = 0; i < 8; i++) row[tid + i * 256] = v[i] * inv;
}

// K4: context[b][d] += partial over t-slice (atomic, ctx pre-zeroed)
__global__ void k4_context(const float* __restrict__ values,
                           const float* __restrict__ w,
                           float* __restrict__ ctx) {
    int b = blockIdx.x;
    int dc = blockIdx.y;           // 8 chunks of 128 d
    int tc = blockIdx.z;           // 8 chunks of 256 t
    int d4 = threadIdx.x & 31;
    int th = threadIdx.x >> 5;     // 8 t-slices of 32
    const float* wrow = w + b * T_;
    int d = dc * 128 + d4 * 4;
    const float* vbase = values + (size_t)b * T_ * D_ + d;
    float4 acc = {0.f, 0.f, 0.f, 0.f};
    int t0 = tc * 256 + th * 32;
    for (int t = t0; t < t0 + 32; t++) {
        float wt = wrow[t];
        float4 vv = *(const float4*)(vbase + (size_t)t * D_);
        acc.x += wt * vv.x;
        acc.y += wt * vv.y;
        acc.z += wt * vv.z;
        acc.w += wt * vv.w;
    }
    __shared__ float4 red4[256];
    red4[threadIdx.x] = acc;
    __syncthreads();
    if (th == 0) {
        float4 s = red4[d4];
        #pragma unroll
        for (int i = 1; i < 8; i++) {
            float4 o = red4[i * 32 + d4];
            s.x += o.x; s.y += o.y; s.z += o.z; s.w += o.w;
        }
        atomicAdd(&ctx[b * D_ + d + 0], s.x);
        atomicAdd(&ctx[b * D_ + d + 1], s.y);
        atomicAdd(&ctx[b * D_ + d + 2], s.z);
        atomicAdd(&ctx[b * D_ + d + 3], s.w);
    }
}

extern "C" void kernel_launch(void* const* d_in, const int* in_sizes, int n_in,
                              void* d_out, int out_size, void* d_ws, size_t ws_size,
                              hipStream_t stream) {
    const float* query  = (const float*)d_in[0];
    const float* values = (const float*)d_in[1];
    const float* W1     = (const float*)d_in[2];
    const float* b1     = (const float*)d_in[3];
    const float* W2     = (const float*)d_in[4];
    const float* b2     = (const float*)d_in[5];
    const float* V      = (const float*)d_in[6];
    const float* bV     = (const float*)d_in[7];

    float* ctx = (float*)d_out;                 // [B, D]
    float* weights = (float*)d_out + B_ * D_;   // [B, T]: scores, then softmax in place

    // ws: W2T_hi (2 MB) | W2T_lo (2 MB) | q_proj (128 KB)
    size_t need = (size_t)2 * N_ * D_ * sizeof(unsigned short) + (size_t)B_ * N_ * sizeof(float);
    if (ws_size < need) return;
    unsigned short* Th = (unsigned short*)d_ws;
    unsigned short* Tl = Th + (size_t)N_ * D_;
    float* qp = (float*)(Tl + (size_t)N_ * D_);

    (void)hipFuncSetAttribute((const void*)k2_score,
                              hipFuncAttributeMaxDynamicSharedMemorySize, SMEM_TOTAL);

    k0_w2t<<<dim3(N_ / 32, D_ / 32), 256, 0, stream>>>(W2, Th, Tl);
    k1_qproj<<<dim3(B_, N_ / 256), 256, 0, stream>>>(query, W1, b1, qp);
    k2_score<<<M_ / BM, 512, SMEM_TOTAL, stream>>>(values, Th, Tl, qp, b2, V, bV, weights);
    k3_softmax<<<B_, 256, 0, stream>>>(weights);
    hipMemsetAsync(ctx, 0, (size_t)B_ * D_ * sizeof(float), stream);
    k4_context<<<dim3(B_, 8, 8), 256, 0, stream>>>(values, weights, ctx);
}

// Round 6
// 492.740 us; speedup vs baseline: 2.7229x; 2.7229x over previous
//
#include <hip/hip_runtime.h>
#include <hip/hip_bf16.h>

#define B_ 32
#define T_ 2048
#define D_ 1024
#define N_ 1024
#define M_ (B_*T_)

#define BM 128
#define BN 128
#define BK 64

typedef short bf16x8 __attribute__((ext_vector_type(8)));
typedef float f32x4 __attribute__((ext_vector_type(4)));
typedef unsigned short us4 __attribute__((ext_vector_type(4)));

__device__ __forceinline__ unsigned short bf16_rn(float x) {
    unsigned u = __float_as_uint(x);
    u += 0x7FFFu + ((u >> 16) & 1u);
    return (unsigned short)(u >> 16);
}

__device__ __forceinline__ void gload_lds16(const void* g, void* l) {
    __builtin_amdgcn_global_load_lds(
        (__attribute__((address_space(1))) void*)(g),
        (__attribute__((address_space(3))) void*)(l), 16, 0, 0);
}

// K0: W2 [D][N] fp32 -> W2T hi/lo bf16 [N][D]
__global__ void k0_w2t(const float* __restrict__ W2,
                       unsigned short* __restrict__ Th,
                       unsigned short* __restrict__ Tl) {
    __shared__ float tile[32][33];
    int n0 = blockIdx.x * 32, d0 = blockIdx.y * 32;
    int tx = threadIdx.x & 31, ty = threadIdx.x >> 5; // 32 x 8
    #pragma unroll
    for (int i = 0; i < 4; i++) {
        int d = d0 + ty + i * 8;
        tile[ty + i * 8][tx] = W2[d * N_ + n0 + tx];
    }
    __syncthreads();
    #pragma unroll
    for (int i = 0; i < 4; i++) {
        int n = n0 + ty + i * 8;
        float v = tile[tx][ty + i * 8];
        unsigned short h = bf16_rn(v);
        float hf = __uint_as_float((unsigned)h << 16);
        unsigned short l = bf16_rn(v - hf);
        Th[n * D_ + d0 + tx] = h;
        Tl[n * D_ + d0 + tx] = l;
    }
}

// K1: q_proj[b][n] = query[b]@W1[:,n] + b1[n]   (fp32)
__global__ void k1_qproj(const float* __restrict__ query,
                         const float* __restrict__ W1,
                         const float* __restrict__ b1,
                         float* __restrict__ qp) {
    int b = blockIdx.x;
    int n = blockIdx.y * 256 + threadIdx.x;
    const float* q = query + b * D_;
    const float* w = W1 + n;
    float s = 0.f;
    #pragma unroll 8
    for (int d = 0; d < D_; d++) s += q[d] * w[d * N_];
    qp[b * N_ + n] = s + b1[n];
}

// K2: fused score GEMM: score[m] = bV + sum_n V[n]*tanh(qp[b][n]+b2[n]+ values[m]@W2[:,n])
// 2-term scheme: A single bf16 (RTN), B bf16 hi/lo. R2-verified structure:
// 128x128x64 tiles, 4 waves (2x2), 16x16x32 frags, 2 barriers/step, all
// staging via global_load_lds (pre-swizzled sources). nt-pass 0 converts A
// fp32->bf16 and caches to ws; passes 1..7 stage A via global_load_lds.
template<bool USE_WS_A>
__global__ __launch_bounds__(256, 2) void k2_score(
    const float* __restrict__ values,
    const unsigned short* __restrict__ W2Th,
    const unsigned short* __restrict__ W2Tl,
    const float* __restrict__ qp,
    const float* __restrict__ b2,
    const float* __restrict__ V,
    const float* __restrict__ bV,
    float* __restrict__ score,
    unsigned short* __restrict__ Ah) {
    __shared__ unsigned short sAh[BM * BK];
    __shared__ unsigned short sBh[BN * BK];
    __shared__ unsigned short sBl[BN * BK];
    __shared__ float red[2 * BM];

    const int tid = threadIdx.x;
    const int lane = tid & 63;
    const int wid = tid >> 6;
    const int wm = wid >> 1, wn = wid & 1;
    const int g = lane >> 4, c16 = lane & 15;

    const int m0 = blockIdx.x * BM;
    const int b = m0 >> 11; // m0 / T_

    // A reg-staging mapping: 16 float4-cols x 16 rows per pass, 8 passes
    const int a_c4 = tid & 15;
    const int a_r0 = tid >> 4;
    // gload_lds staging mapping (per-wave, 8 rows x 8 chunks per instr)
    const int b_rl = lane >> 3;
    const int b_j = lane & 7;

    float rowpart[16];
    #pragma unroll
    for (int i = 0; i < 16; i++) rowpart[i] = 0.f;

    for (int nt = 0; nt < N_ / BN; nt++) {
        f32x4 acc[4][4];
        #pragma unroll
        for (int mi = 0; mi < 4; mi++)
            #pragma unroll
            for (int ni = 0; ni < 4; ni++) {
                f32x4 z = {0.f, 0.f, 0.f, 0.f};
                acc[mi][ni] = z;
            }

        for (int kt = 0; kt < D_ / BK; kt++) {
            const int k0 = kt * BK;
            __syncthreads(); // previous compute done before LDS overwrite

            // --- B tiles: global_load_lds from pre-split W2T, source pre-swizzled
            #pragma unroll
            for (int i = 0; i < 4; i++) {
                int r = wid * 32 + i * 8 + b_rl;
                int jj = b_j ^ (r & 7);
                size_t soff = (size_t)(nt * BN + r) * D_ + k0 + jj * 8;
                gload_lds16(W2Th + soff, &sBh[(wid * 32 + i * 8) * 64]);
                gload_lds16(W2Tl + soff, &sBl[(wid * 32 + i * 8) * 64]);
            }

            if (USE_WS_A && nt > 0) {
                // --- A tile from bf16 ws cache, gload_lds, pre-swizzled source
                #pragma unroll
                for (int i = 0; i < 4; i++) {
                    int r = wid * 32 + i * 8 + b_rl;
                    int jj = b_j ^ (r & 7);
                    size_t soff = (size_t)(m0 + r) * D_ + k0 + jj * 8;
                    gload_lds16(Ah + soff, &sAh[(wid * 32 + i * 8) * 64]);
                }
            } else {
                // --- A tile: fp32 -> bf16 (RTN), swizzled ds_write
                const float* abase = values + (size_t)m0 * D_ + k0;
                #pragma unroll
                for (int p = 0; p < 8; p++) {
                    int r = p * 16 + a_r0;
                    float4 v = *(const float4*)(abase + (size_t)r * D_ + a_c4 * 4);
                    float vv[4] = {v.x, v.y, v.z, v.w};
                    us4 hv;
                    #pragma unroll
                    for (int q = 0; q < 4; q++)
                        hv[q] = bf16_rn(vv[q]);
                    int idx = r * 64 + ((((a_c4 >> 1) ^ (r & 7)) << 3) | ((a_c4 & 1) << 2));
                    *(us4*)&sAh[idx] = hv;
                    if (USE_WS_A) {
                        // linear [M][D] store for passes 1..7
                        size_t goff = (size_t)(m0 + r) * D_ + k0 + a_c4 * 4;
                        *(us4*)&Ah[goff] = hv;
                    }
                }
            }

            __syncthreads(); // drains vmcnt (gload_lds/stores) + lgkm (ds_write)

            #pragma unroll
            for (int s = 0; s < 2; s++) {
                bf16x8 aH[4], bH[4], bL[4];
                #pragma unroll
                for (int mi = 0; mi < 4; mi++) {
                    int r = wm * 64 + mi * 16 + c16;
                    int idx = r * 64 + (((s * 4 + g) ^ (r & 7)) << 3);
                    aH[mi] = *(const bf16x8*)&sAh[idx];
                }
                #pragma unroll
                for (int ni = 0; ni < 4; ni++) {
                    int r = wn * 64 + ni * 16 + c16;
                    int idx = r * 64 + (((s * 4 + g) ^ (r & 7)) << 3);
                    bH[ni] = *(const bf16x8*)&sBh[idx];
                    bL[ni] = *(const bf16x8*)&sBl[idx];
                }
                #pragma unroll
                for (int mi = 0; mi < 4; mi++)
                    #pragma unroll
                    for (int ni = 0; ni < 4; ni++) {
                        acc[mi][ni] = __builtin_amdgcn_mfma_f32_16x16x32_bf16(aH[mi], bH[ni], acc[mi][ni], 0, 0, 0);
                        acc[mi][ni] = __builtin_amdgcn_mfma_f32_16x16x32_bf16(aH[mi], bL[ni], acc[mi][ni], 0, 0, 0);
                    }
            }
        }

        // --- epilogue: accumulate V[n]*tanh(acc + qp + b2) into row partials
        #pragma unroll
        for (int ni = 0; ni < 4; ni++) {
            int n = nt * BN + wn * 64 + ni * 16 + c16;
            float qv = qp[b * N_ + n] + b2[n];
            float Vv = V[n];
            #pragma unroll
            for (int mi = 0; mi < 4; mi++)
                #pragma unroll
                for (int r = 0; r < 4; r++) {
                    rowpart[mi * 4 + r] += tanhf(acc[mi][ni][r] + qv) * Vv;
                }
        }
    }

    // reduce across the 16 n-lanes of each group
    #pragma unroll
    for (int i = 0; i < 16; i++) {
        float v = rowpart[i];
        v += __shfl_xor(v, 1);
        v += __shfl_xor(v, 2);
        v += __shfl_xor(v, 4);
        v += __shfl_xor(v, 8);
        rowpart[i] = v;
    }
    if (c16 == 0) {
        #pragma unroll
        for (int mi = 0; mi < 4; mi++)
            #pragma unroll
            for (int r = 0; r < 4; r++)
                red[wn * BM + wm * 64 + mi * 16 + g * 4 + r] = rowpart[mi * 4 + r];
    }
    __syncthreads();
    if (tid < BM) {
        score[m0 + tid] = red[tid] + red[BM + tid] + bV[0];
    }
}

// K3: softmax over T per batch, in place
__global__ void k3_softmax(float* __restrict__ sw) {
    int b = blockIdx.x;
    float* row = sw + b * T_;
    int tid = threadIdx.x;
    float v[8];
    float lmax = -1e30f;
    #pragma unroll
    for (int i = 0; i < 8; i++) {
        v[i] = row[tid + i * 256];
        lmax = fmaxf(lmax, v[i]);
    }
    #pragma unroll
    for (int d = 1; d < 64; d <<= 1) lmax = fmaxf(lmax, __shfl_xor(lmax, d));
    __shared__ float sm[4], ss[4];
    if ((tid & 63) == 0) sm[tid >> 6] = lmax;
    __syncthreads();
    lmax = fmaxf(fmaxf(sm[0], sm[1]), fmaxf(sm[2], sm[3]));
    float lsum = 0.f;
    #pragma unroll
    for (int i = 0; i < 8; i++) {
        v[i] = expf(v[i] - lmax);
        lsum += v[i];
    }
    #pragma unroll
    for (int d = 1; d < 64; d <<= 1) lsum += __shfl_xor(lsum, d);
    if ((tid & 63) == 0) ss[tid >> 6] = lsum;
    __syncthreads();
    lsum = ss[0] + ss[1] + ss[2] + ss[3];
    float inv = 1.f / lsum;
    #pragma unroll
    for (int i = 0; i < 8; i++) row[tid + i * 256] = v[i] * inv;
}

// K4: context[b][d] += partial over t-slice (atomic, ctx pre-zeroed)
__global__ void k4_context(const float* __restrict__ values,
                           const float* __restrict__ w,
                           float* __restrict__ ctx) {
    int b = blockIdx.x;
    int dc = blockIdx.y;           // 8 chunks of 128 d
    int tc = blockIdx.z;           // 8 chunks of 256 t
    int d4 = threadIdx.x & 31;
    int th = threadIdx.x >> 5;     // 8 t-slices of 32
    const float* wrow = w + b * T_;
    int d = dc * 128 + d4 * 4;
    const float* vbase = values + (size_t)b * T_ * D_ + d;
    float4 acc = {0.f, 0.f, 0.f, 0.f};
    int t0 = tc * 256 + th * 32;
    for (int t = t0; t < t0 + 32; t++) {
        float wt = wrow[t];
        float4 vv = *(const float4*)(vbase + (size_t)t * D_);
        acc.x += wt * vv.x;
        acc.y += wt * vv.y;
        acc.z += wt * vv.z;
        acc.w += wt * vv.w;
    }
    __shared__ float4 red4[256];
    red4[threadIdx.x] = acc;
    __syncthreads();
    if (th == 0) {
        float4 s = red4[d4];
        #pragma unroll
        for (int i = 1; i < 8; i++) {
            float4 o = red4[i * 32 + d4];
            s.x += o.x; s.y += o.y; s.z += o.z; s.w += o.w;
        }
        atomicAdd(&ctx[b * D_ + d + 0], s.x);
        atomicAdd(&ctx[b * D_ + d + 1], s.y);
        atomicAdd(&ctx[b * D_ + d + 2], s.z);
        atomicAdd(&ctx[b * D_ + d + 3], s.w);
    }
}

extern "C" void kernel_launch(void* const* d_in, const int* in_sizes, int n_in,
                              void* d_out, int out_size, void* d_ws, size_t ws_size,
                              hipStream_t stream) {
    const float* query  = (const float*)d_in[0];
    const float* values = (const float*)d_in[1];
    const float* W1     = (const float*)d_in[2];
    const float* b1     = (const float*)d_in[3];
    const float* W2     = (const float*)d_in[4];
    const float* b2     = (const float*)d_in[5];
    const float* V      = (const float*)d_in[6];
    const float* bV     = (const float*)d_in[7];

    float* ctx = (float*)d_out;                 // [B, D]
    float* weights = (float*)d_out + B_ * D_;   // [B, T]: scores, then softmax in place

    // ws: W2T_hi (2 MB) | W2T_lo (2 MB) | q_proj (128 KB) | A_hi (128 MB)
    size_t need_base = (size_t)2 * N_ * D_ * sizeof(unsigned short) + (size_t)B_ * N_ * sizeof(float);
    size_t need_full = need_base + (size_t)M_ * D_ * sizeof(unsigned short);
    if (ws_size < need_base) return;
    unsigned short* Th = (unsigned short*)d_ws;
    unsigned short* Tl = Th + (size_t)N_ * D_;
    float* qp = (float*)(Tl + (size_t)N_ * D_);
    unsigned short* Ahi = (unsigned short*)(qp + (size_t)B_ * N_);

    k0_w2t<<<dim3(N_ / 32, D_ / 32), 256, 0, stream>>>(W2, Th, Tl);
    k1_qproj<<<dim3(B_, N_ / 256), 256, 0, stream>>>(query, W1, b1, qp);
    if (ws_size >= need_full) {
        k2_score<true><<<M_ / BM, 256, 0, stream>>>(values, Th, Tl, qp, b2, V, bV, weights, Ahi);
    } else {
        k2_score<false><<<M_ / BM, 256, 0, stream>>>(values, Th, Tl, qp, b2, V, bV, weights, Ahi);
    }
    k3_softmax<<<B_, 256, 0, stream>>>(weights);
    hipMemsetAsync(ctx, 0, (size_t)B_ * D_ * sizeof(float), stream);
    k4_context<<<dim3(B_, 8, 8), 256, 0, stream>>>(values, weights, ctx);
}

// Round 7
// 381.249 us; speedup vs baseline: 3.5191x; 1.2924x over previous
//
#include <hip/hip_runtime.h>
#include <hip/hip_bf16.h>

#define B_ 32
#define T_ 2048
#define D_ 1024
#define N_ 1024
#define M_ (B_*T_)

#define BM 64
#define BN 128
#define BK 64

typedef short bf16x8 __attribute__((ext_vector_type(8)));
typedef float f32x4 __attribute__((ext_vector_type(4)));
typedef unsigned short us4 __attribute__((ext_vector_type(4)));

__device__ __forceinline__ unsigned short bf16_rn(float x) {
    unsigned u = __float_as_uint(x);
    u += 0x7FFFu + ((u >> 16) & 1u);
    return (unsigned short)(u >> 16);
}

__device__ __forceinline__ void gload_lds16(const void* g, void* l) {
    __builtin_amdgcn_global_load_lds(
        (__attribute__((address_space(1))) void*)(g),
        (__attribute__((address_space(3))) void*)(l), 16, 0, 0);
}

// K0: W2 [D][N] fp32 -> W2T bf16 (RTN) [N][D]
__global__ void k0_w2t(const float* __restrict__ W2,
                       unsigned short* __restrict__ Th) {
    __shared__ float tile[32][33];
    int n0 = blockIdx.x * 32, d0 = blockIdx.y * 32;
    int tx = threadIdx.x & 31, ty = threadIdx.x >> 5; // 32 x 8
    #pragma unroll
    for (int i = 0; i < 4; i++) {
        int d = d0 + ty + i * 8;
        tile[ty + i * 8][tx] = W2[d * N_ + n0 + tx];
    }
    __syncthreads();
    #pragma unroll
    for (int i = 0; i < 4; i++) {
        int n = n0 + ty + i * 8;
        Th[n * D_ + d0 + tx] = bf16_rn(tile[tx][ty + i * 8]);
    }
}

// K1: q_proj[b][n] = query[b]@W1[:,n] + b1[n]   (fp32)
__global__ void k1_qproj(const float* __restrict__ query,
                         const float* __restrict__ W1,
                         const float* __restrict__ b1,
                         float* __restrict__ qp) {
    int b = blockIdx.x;
    int n = blockIdx.y * 256 + threadIdx.x;
    const float* q = query + b * D_;
    const float* w = W1 + n;
    float s = 0.f;
    #pragma unroll 8
    for (int d = 0; d < D_; d++) s += q[d] * w[d * N_];
    qp[b * N_ + n] = s + b1[n];
}

// K2: fused score GEMM: score[m] = bV + sum_n V[n]*tanh(qp[b][n]+b2[n]+ values[m]@W2[:,n])
// Single-bf16 A x single-bf16 B (RTN both; error budget verified via R4/R6
// measurements: each side contributes ~4.9e-4, combined ~7e-4 < 2.05e-3).
// R2/R6-verified structure: 64x128x64 tiles, 4 waves (2x2), 16x16x32 frags,
// 2 barriers/K-step, all staging via global_load_lds with pre-swizzled
// sources. nt-pass 0 converts A fp32->bf16 and caches to ws; passes 1..7
// stage A via global_load_lds. Grid = 1024 blocks -> 4 blocks/CU.
template<bool USE_WS_A>
__global__ __launch_bounds__(256, 2) void k2_score(
    const float* __restrict__ values,
    const unsigned short* __restrict__ W2Th,
    const float* __restrict__ qp,
    const float* __restrict__ b2,
    const float* __restrict__ V,
    const float* __restrict__ bV,
    float* __restrict__ score,
    unsigned short* __restrict__ Ah) {
    __shared__ unsigned short sAh[BM * BK];   // 8 KB
    __shared__ unsigned short sBh[BN * BK];   // 16 KB
    __shared__ float red[2 * BM];

    const int tid = threadIdx.x;
    const int lane = tid & 63;
    const int wid = tid >> 6;
    const int wm = wid >> 1, wn = wid & 1;    // wave tile 32x64
    const int g = lane >> 4, c16 = lane & 15;

    const int m0 = blockIdx.x * BM;
    const int b = m0 >> 11; // m0 / T_

    // A reg-staging mapping (pass 0): 16 float4-cols x 16 rows per pass, 4 passes
    const int a_c4 = tid & 15;
    const int a_r0 = tid >> 4;
    // gload_lds staging mapping (per-wave, 8 rows x 8 chunks per instr)
    const int b_rl = lane >> 3;
    const int b_j = lane & 7;

    float rowpart[8];
    #pragma unroll
    for (int i = 0; i < 8; i++) rowpart[i] = 0.f;

    for (int nt = 0; nt < N_ / BN; nt++) {
        f32x4 acc[2][4];
        #pragma unroll
        for (int mi = 0; mi < 2; mi++)
            #pragma unroll
            for (int ni = 0; ni < 4; ni++) {
                f32x4 z = {0.f, 0.f, 0.f, 0.f};
                acc[mi][ni] = z;
            }

        for (int kt = 0; kt < D_ / BK; kt++) {
            const int k0 = kt * BK;
            __syncthreads(); // previous compute done before LDS overwrite

            // --- B tile: global_load_lds from pre-converted W2T, source pre-swizzled
            #pragma unroll
            for (int i = 0; i < 4; i++) {
                int r = wid * 32 + i * 8 + b_rl;
                int jj = b_j ^ (r & 7);
                size_t soff = (size_t)(nt * BN + r) * D_ + k0 + jj * 8;
                gload_lds16(W2Th + soff, &sBh[(wid * 32 + i * 8) * 64]);
            }

            if (USE_WS_A && nt > 0) {
                // --- A tile from bf16 ws cache, gload_lds, pre-swizzled source
                #pragma unroll
                for (int i = 0; i < 2; i++) {
                    int r = wid * 16 + i * 8 + b_rl;
                    int jj = b_j ^ (r & 7);
                    size_t soff = (size_t)(m0 + r) * D_ + k0 + jj * 8;
                    gload_lds16(Ah + soff, &sAh[(wid * 16 + i * 8) * 64]);
                }
            } else {
                // --- A tile: fp32 -> bf16 (RTN), swizzled ds_write
                const float* abase = values + (size_t)m0 * D_ + k0;
                #pragma unroll
                for (int p = 0; p < 4; p++) {
                    int r = p * 16 + a_r0;
                    float4 v = *(const float4*)(abase + (size_t)r * D_ + a_c4 * 4);
                    float vv[4] = {v.x, v.y, v.z, v.w};
                    us4 hv;
                    #pragma unroll
                    for (int q = 0; q < 4; q++)
                        hv[q] = bf16_rn(vv[q]);
                    int idx = r * 64 + ((((a_c4 >> 1) ^ (r & 7)) << 3) | ((a_c4 & 1) << 2));
                    *(us4*)&sAh[idx] = hv;
                    if (USE_WS_A) {
                        // linear [M][D] store for passes 1..7
                        size_t goff = (size_t)(m0 + r) * D_ + k0 + a_c4 * 4;
                        *(us4*)&Ah[goff] = hv;
                    }
                }
            }

            __syncthreads(); // drains vmcnt (gload_lds/stores) + lgkm (ds_write)

            #pragma unroll
            for (int s = 0; s < 2; s++) {
                bf16x8 aH[2], bH[4];
                #pragma unroll
                for (int mi = 0; mi < 2; mi++) {
                    int r = wm * 32 + mi * 16 + c16;
                    int idx = r * 64 + (((s * 4 + g) ^ (r & 7)) << 3);
                    aH[mi] = *(const bf16x8*)&sAh[idx];
                }
                #pragma unroll
                for (int ni = 0; ni < 4; ni++) {
                    int r = wn * 64 + ni * 16 + c16;
                    int idx = r * 64 + (((s * 4 + g) ^ (r & 7)) << 3);
                    bH[ni] = *(const bf16x8*)&sBh[idx];
                }
                #pragma unroll
                for (int mi = 0; mi < 2; mi++)
                    #pragma unroll
                    for (int ni = 0; ni < 4; ni++)
                        acc[mi][ni] = __builtin_amdgcn_mfma_f32_16x16x32_bf16(aH[mi], bH[ni], acc[mi][ni], 0, 0, 0);
            }
        }

        // --- epilogue: accumulate V[n]*tanh(acc + qp + b2) into row partials
        #pragma unroll
        for (int ni = 0; ni < 4; ni++) {
            int n = nt * BN + wn * 64 + ni * 16 + c16;
            float qv = qp[b * N_ + n] + b2[n];
            float Vv = V[n];
            #pragma unroll
            for (int mi = 0; mi < 2; mi++)
                #pragma unroll
                for (int r = 0; r < 4; r++) {
                    rowpart[mi * 4 + r] += tanhf(acc[mi][ni][r] + qv) * Vv;
                }
        }
    }

    // reduce across the 16 n-lanes of each group
    #pragma unroll
    for (int i = 0; i < 8; i++) {
        float v = rowpart[i];
        v += __shfl_xor(v, 1);
        v += __shfl_xor(v, 2);
        v += __shfl_xor(v, 4);
        v += __shfl_xor(v, 8);
        rowpart[i] = v;
    }
    if (c16 == 0) {
        #pragma unroll
        for (int mi = 0; mi < 2; mi++)
            #pragma unroll
            for (int r = 0; r < 4; r++)
                red[wn * BM + wm * 32 + mi * 16 + g * 4 + r] = rowpart[mi * 4 + r];
    }
    __syncthreads();
    if (tid < BM) {
        score[m0 + tid] = red[tid] + red[BM + tid] + bV[0];
    }
}

// K3: softmax over T per batch, in place
__global__ void k3_softmax(float* __restrict__ sw) {
    int b = blockIdx.x;
    float* row = sw + b * T_;
    int tid = threadIdx.x;
    float v[8];
    float lmax = -1e30f;
    #pragma unroll
    for (int i = 0; i < 8; i++) {
        v[i] = row[tid + i * 256];
        lmax = fmaxf(lmax, v[i]);
    }
    #pragma unroll
    for (int d = 1; d < 64; d <<= 1) lmax = fmaxf(lmax, __shfl_xor(lmax, d));
    __shared__ float sm[4], ss[4];
    if ((tid & 63) == 0) sm[tid >> 6] = lmax;
    __syncthreads();
    lmax = fmaxf(fmaxf(sm[0], sm[1]), fmaxf(sm[2], sm[3]));
    float lsum = 0.f;
    #pragma unroll
    for (int i = 0; i < 8; i++) {
        v[i] = expf(v[i] - lmax);
        lsum += v[i];
    }
    #pragma unroll
    for (int d = 1; d < 64; d <<= 1) lsum += __shfl_xor(lsum, d);
    if ((tid & 63) == 0) ss[tid >> 6] = lsum;
    __syncthreads();
    lsum = ss[0] + ss[1] + ss[2] + ss[3];
    float inv = 1.f / lsum;
    #pragma unroll
    for (int i = 0; i < 8; i++) row[tid + i * 256] = v[i] * inv;
}

// K4: context[b][d] += partial over t-slice (atomic, ctx pre-zeroed)
__global__ void k4_context(const float* __restrict__ values,
                           const float* __restrict__ w,
                           float* __restrict__ ctx) {
    int b = blockIdx.x;
    int dc = blockIdx.y;           // 8 chunks of 128 d
    int tc = blockIdx.z;           // 8 chunks of 256 t
    int d4 = threadIdx.x & 31;
    int th = threadIdx.x >> 5;     // 8 t-slices of 32
    const float* wrow = w + b * T_;
    int d = dc * 128 + d4 * 4;
    const float* vbase = values + (size_t)b * T_ * D_ + d;
    float4 acc = {0.f, 0.f, 0.f, 0.f};
    int t0 = tc * 256 + th * 32;
    for (int t = t0; t < t0 + 32; t++) {
        float wt = wrow[t];
        float4 vv = *(const float4*)(vbase + (size_t)t * D_);
        acc.x += wt * vv.x;
        acc.y += wt * vv.y;
        acc.z += wt * vv.z;
        acc.w += wt * vv.w;
    }
    __shared__ float4 red4[256];
    red4[threadIdx.x] = acc;
    __syncthreads();
    if (th == 0) {
        float4 s = red4[d4];
        #pragma unroll
        for (int i = 1; i < 8; i++) {
            float4 o = red4[i * 32 + d4];
            s.x += o.x; s.y += o.y; s.z += o.z; s.w += o.w;
        }
        atomicAdd(&ctx[b * D_ + d + 0], s.x);
        atomicAdd(&ctx[b * D_ + d + 1], s.y);
        atomicAdd(&ctx[b * D_ + d + 2], s.z);
        atomicAdd(&ctx[b * D_ + d + 3], s.w);
    }
}

extern "C" void kernel_launch(void* const* d_in, const int* in_sizes, int n_in,
                              void* d_out, int out_size, void* d_ws, size_t ws_size,
                              hipStream_t stream) {
    const float* query  = (const float*)d_in[0];
    const float* values = (const float*)d_in[1];
    const float* W1     = (const float*)d_in[2];
    const float* b1     = (const float*)d_in[3];
    const float* W2     = (const float*)d_in[4];
    const float* b2     = (const float*)d_in[5];
    const float* V      = (const float*)d_in[6];
    const float* bV     = (const float*)d_in[7];

    float* ctx = (float*)d_out;                 // [B, D]
    float* weights = (float*)d_out + B_ * D_;   // [B, T]: scores, then softmax in place

    // ws: W2T (2 MB) | q_proj (128 KB) | A_hi (128 MB)
    size_t need_base = (size_t)N_ * D_ * sizeof(unsigned short) + (size_t)B_ * N_ * sizeof(float);
    size_t need_full = need_base + (size_t)M_ * D_ * sizeof(unsigned short);
    if (ws_size < need_base) return;
    unsigned short* Th = (unsigned short*)d_ws;
    float* qp = (float*)(Th + (size_t)N_ * D_);
    unsigned short* Ahi = (unsigned short*)(qp + (size_t)B_ * N_);

    k0_w2t<<<dim3(N_ / 32, D_ / 32), 256, 0, stream>>>(W2, Th);
    k1_qproj<<<dim3(B_, N_ / 256), 256, 0, stream>>>(query, W1, b1, qp);
    if (ws_size >= need_full) {
        k2_score<true><<<M_ / BM, 256, 0, stream>>>(values, Th, qp, b2, V, bV, weights, Ahi);
    } else {
        k2_score<false><<<M_ / BM, 256, 0, stream>>>(values, Th, qp, b2, V, bV, weights, Ahi);
    }
    k3_softmax<<<B_, 256, 0, stream>>>(weights);
    hipMemsetAsync(ctx, 0, (size_t)B_ * D_ * sizeof(float), stream);
    k4_context<<<dim3(B_, 8, 8), 256, 0, stream>>>(values, weights, ctx);
}